// Round 1
// baseline (1118.529 us; speedup 1.0000x reference)
//
#include <hip/hip_runtime.h>
#include <stdint.h>

#define VN   1000000
#define VDIM 256
#define GDIM 256
#define NH   16
#define NG   50000
#define HIDD 128

using bf16x8 = __attribute__((ext_vector_type(8))) __bf16;
using f32x4  = __attribute__((ext_vector_type(4))) float;
using u16x4  = __attribute__((ext_vector_type(4))) unsigned short;
using u16x8  = __attribute__((ext_vector_type(8))) unsigned short;

__device__ __forceinline__ unsigned short f2bf(float f) {
  unsigned u = __float_as_uint(f);
  return (unsigned short)((u + 0x7FFFu + ((u >> 16) & 1u)) >> 16);  // RNE
}
__device__ __forceinline__ float bf2f(unsigned short h) {
  return __uint_as_float(((unsigned)h) << 16);
}
__device__ __forceinline__ f32x4 fzero4() { f32x4 z = {0.f, 0.f, 0.f, 0.f}; return z; }

// ---------------- weight prep: fp32 -> bf16 in MFMA B-fragment order ----------------
// For W[K][N]: frag element idx = ((c*(K/32)+s)*64 + lane)*8 + j  holds W[32s+8*(lane>>4)+j][16c+(lane&15)]
__global__ void k_prep(const float* __restrict__ s1, const float* __restrict__ s2,
                       const float* __restrict__ t1, const float* __restrict__ t2,
                       unsigned short* __restrict__ WB) {
  int t = blockIdx.x * 256 + threadIdx.x;
  const float* W; unsigned short* dst; int K, N, lid;
  if (t < 32768)       { W = s1; dst = WB;          K = 256; N = 128; lid = t; }
  else if (t < 65536)  { W = t1; dst = WB + 32768;  K = 256; N = 128; lid = t - 32768; }
  else if (t < 98304)  { W = t2; dst = WB + 65536;  K = 128; N = 256; lid = t - 65536; }
  else if (t < 100352) { W = s2; dst = WB + 98304;  K = 128; N = 16;  lid = t - 98304; }
  else return;
  int j = lid & 7, l = (lid >> 3) & 63, rem = lid >> 9;
  int KS = K >> 5;
  int s = rem % KS, c = rem / KS;
  int row = 32 * s + 8 * (l >> 4) + j;
  int col = 16 * c + (l & 15);
  dst[lid] = f2bf(W[row * N + col]);
}

// ---------------- graph start offsets (seg is sorted) ----------------
__global__ void k_offsets(const int* __restrict__ seg, int* __restrict__ off) {
  int g = blockIdx.x * 256 + threadIdx.x;
  if (g > NG) return;
  int lo = 0, hi = VN;
  while (lo < hi) { int mid = (lo + hi) >> 1; if (seg[mid] < g) lo = mid + 1; else hi = mid; }
  off[g] = lo;
}

__global__ void k_zero(float* __restrict__ out) {
  int i = blockIdx.x * 256 + threadIdx.x;
  float4 z = make_float4(0.f, 0.f, 0.f, 0.f);
  if (i < NG * GDIM / 4) ((float4*)out)[i] = z;
}

// ---------------- front: X -> scores (fp32) + T1 (bf16) ----------------
__global__ __launch_bounds__(256) void k_front(
    const float* __restrict__ X,
    const unsigned short* __restrict__ WBs1,
    const unsigned short* __restrict__ WBt1,
    const unsigned short* __restrict__ WBs2,
    float* __restrict__ scores,
    unsigned short* __restrict__ T1out) {
  __shared__ __align__(16) char U[49152];  // [0,32768) Xs (alias Ts) ; [32768,49152) Hs
  char* const Xs = U;
  char* const Hs = U + 32768;
  char* const Ts = U;

  const int tid  = threadIdx.x;
  const int lane = tid & 63;
  const int w    = tid >> 6;
  const size_t base = (size_t)blockIdx.x * 64;

  // stage X tile -> bf16 LDS, rows of 512B, XOR swizzle byte^=((row&7)<<4)
  {
    const float4* Xg = (const float4*)(X + base * VDIM);
    #pragma unroll
    for (int i = 0; i < 16; ++i) {
      int f = tid + 256 * i;
      int row = f >> 6, c4 = f & 63;
      float4 v = Xg[f];
      u16x4 b = { f2bf(v.x), f2bf(v.y), f2bf(v.z), f2bf(v.w) };
      *(u16x4*)(Xs + row * 512 + ((c4 * 8) ^ ((row & 7) << 4))) = b;
    }
  }
  __syncthreads();

  // layer 1: C1[64][256] = relu(X @ [Sw1|Tw1]); waves 0,1 -> Sw1 cols, waves 2,3 -> Tw1 cols
  const unsigned short* WB = (w < 2) ? WBs1 : WBt1;
  const int cbase = (w & 1) * 4;  // col-frags cbase..cbase+3 within the 128-col half
  f32x4 acc[4][4];
  #pragma unroll
  for (int r = 0; r < 4; ++r)
    #pragma unroll
    for (int c = 0; c < 4; ++c) acc[r][c] = fzero4();

  #pragma unroll
  for (int ks = 0; ks < 8; ++ks) {
    bf16x8 A[4];
    #pragma unroll
    for (int r = 0; r < 4; ++r) {
      int row = 16 * r + (lane & 15);
      int cb = 64 * ks + 16 * (lane >> 4);
      A[r] = *(const bf16x8*)(Xs + row * 512 + (cb ^ ((row & 7) << 4)));
    }
    #pragma unroll
    for (int ci = 0; ci < 4; ++ci) {
      bf16x8 B = *(const bf16x8*)(WB + (size_t)(((cbase + ci) * 8 + ks) * 64 + lane) * 8);
      #pragma unroll
      for (int r = 0; r < 4; ++r)
        acc[r][ci] = __builtin_amdgcn_mfma_f32_16x16x32_bf16(A[r], B, acc[r][ci], 0, 0, 0);
    }
  }
  __syncthreads();  // everyone done reading Xs

  // write C1: relu + bf16. waves 0-1 -> Hs (H1), waves 2-3 -> Ts (T1), [64][128] 256B rows
  {
    char* const dst = (w < 2) ? Hs : Ts;
    #pragma unroll
    for (int ci = 0; ci < 4; ++ci) {
      int colf = cbase + ci;
      #pragma unroll
      for (int r = 0; r < 4; ++r) {
        #pragma unroll
        for (int j = 0; j < 4; ++j) {
          int row = 16 * r + 4 * (lane >> 4) + j;
          int col = 16 * colf + (lane & 15);
          float v = acc[r][ci][j];
          v = v > 0.f ? v : 0.f;
          *(unsigned short*)(dst + row * 256 + ((col * 2) ^ ((row & 7) << 4))) = f2bf(v);
        }
      }
    }
  }
  __syncthreads();

  // T1 tile -> global, coalesced 16B/lane
  {
    #pragma unroll
    for (int i = 0; i < 4; ++i) {
      int f = tid + 256 * i;           // 1024 chunks of 16B
      int row = f >> 4, c16 = f & 15;
      u16x8 v = *(const u16x8*)(Ts + row * 256 + ((c16 * 16) ^ ((row & 7) << 4)));
      *(u16x8*)(T1out + base * HIDD + (size_t)f * 8) = v;
    }
  }

  // scores = H1 @ Sw2 : wave w -> row-frag w
  {
    f32x4 sa = fzero4();
    #pragma unroll
    for (int ks = 0; ks < 4; ++ks) {
      int row = 16 * w + (lane & 15);
      int cb = 64 * ks + 16 * (lane >> 4);
      bf16x8 A2 = *(const bf16x8*)(Hs + row * 256 + (cb ^ ((row & 7) << 4)));
      bf16x8 B2 = *(const bf16x8*)(WBs2 + (size_t)(ks * 64 + lane) * 8);
      sa = __builtin_amdgcn_mfma_f32_16x16x32_bf16(A2, B2, sa, 0, 0, 0);
    }
    #pragma unroll
    for (int j = 0; j < 4; ++j) {
      int row = 16 * w + 4 * (lane >> 4) + j;
      scores[(base + row) * NH + (lane & 15)] = sa[j];
    }
  }
}

// ---------------- segment softmax, in place: scores -> weights ----------------
__global__ void k_softmax(float* __restrict__ sc, const int* __restrict__ off) {
  int g = blockIdx.x * 4 + (threadIdx.x >> 6);
  int lane = threadIdx.x & 63;
  if (g >= NG) return;
  int o0 = off[g], o1 = off[g + 1];
  int n = o1 - o0;
  if (n <= 0) return;
  int h = lane & 15, sl = lane >> 4;   // 16 heads x 4 node-slices per wave
  float m = -3.4e38f;
  for (int i = sl; i < n; i += 4) m = fmaxf(m, sc[(size_t)(o0 + i) * NH + h]);
  m = fmaxf(m, __shfl_xor(m, 16, 64));
  m = fmaxf(m, __shfl_xor(m, 32, 64));
  float s = 0.f;
  for (int i = sl; i < n; i += 4) s += __expf(sc[(size_t)(o0 + i) * NH + h] - m);
  s += __shfl_xor(s, 16, 64);
  s += __shfl_xor(s, 32, 64);
  float rs = 1.0f / s;
  for (int i = sl; i < n; i += 4) {
    size_t idx = (size_t)(o0 + i) * NH + h;
    sc[idx] = __expf(sc[idx] - m) * rs;
  }
}

// ---------------- back: T1 -> relu(T1@Tw2) * weights -> segment sum ----------------
__global__ __launch_bounds__(256) void k_back(
    const unsigned short* __restrict__ T1,
    const unsigned short* __restrict__ WBt2,
    const float* __restrict__ wgt,
    const int* __restrict__ seg,
    const int* __restrict__ off,
    float* __restrict__ out) {
  __shared__ __align__(16) char U2[32768];  // T1s [0,16384) | wvs [0,32768)
  __shared__ float wl[64 * 16];
  __shared__ int sl[64];

  const int tid  = threadIdx.x;
  const int lane = tid & 63;
  const int w    = tid >> 6;

  // graph-aligned node partition: graphs starting in [lo,hi)
  const int lo = blockIdx.x * 256;
  const int hi = (lo + 256 < VN) ? (lo + 256) : VN;
  int g0, g1;
  { int a = 0, b = NG; while (a < b) { int m = (a + b) >> 1; if (off[m] < lo) a = m + 1; else b = m; } g0 = a; }
  { int a = 0, b = NG; while (a < b) { int m = (a + b) >> 1; if (off[m] < hi) a = m + 1; else b = m; } g1 = a; }
  const int n0 = off[g0], n1 = off[g1];

  float a0 = 0.f, a1 = 0.f, a2 = 0.f, a3 = 0.f;
  int cur_g = -1;

  for (int cb = n0; cb < n1; cb += 64) {
    const int cn = (n1 - cb < 64) ? (n1 - cb) : 64;
    // stage T1 tile (swizzled 256B rows), weights, seg
    #pragma unroll
    for (int i = 0; i < 4; ++i) {
      int f = tid + 256 * i;
      int row = f >> 4, c16 = f & 15;
      u16x8 v = {0, 0, 0, 0, 0, 0, 0, 0};
      if (row < cn) v = *(const u16x8*)(T1 + (size_t)(cb + row) * HIDD + (size_t)c16 * 8);
      *(u16x8*)(U2 + row * 256 + ((c16 * 16) ^ ((row & 7) << 4))) = v;
    }
    #pragma unroll
    for (int i = 0; i < 4; ++i) {
      int f = tid + 256 * i;
      int row = f >> 4;
      wl[f] = (row < cn) ? wgt[(size_t)(cb + row) * NH + (f & 15)] : 0.f;
    }
    if (tid < 64) sl[tid] = (tid < cn) ? seg[cb + tid] : -1;
    __syncthreads();

    // R = relu(T1s @ Tw2); wave w -> col-frags 4w..4w+3
    f32x4 racc[4][4];
    #pragma unroll
    for (int r = 0; r < 4; ++r)
      #pragma unroll
      for (int c = 0; c < 4; ++c) racc[r][c] = fzero4();
    #pragma unroll
    for (int ks = 0; ks < 4; ++ks) {
      bf16x8 A[4];
      #pragma unroll
      for (int r = 0; r < 4; ++r) {
        int row = 16 * r + (lane & 15);
        int cbyte = 64 * ks + 16 * (lane >> 4);
        A[r] = *(const bf16x8*)(U2 + row * 256 + (cbyte ^ ((row & 7) << 4)));
      }
      #pragma unroll
      for (int ci = 0; ci < 4; ++ci) {
        int cf = 4 * w + ci;
        bf16x8 B = *(const bf16x8*)(WBt2 + (size_t)((cf * 4 + ks) * 64 + lane) * 8);
        #pragma unroll
        for (int r = 0; r < 4; ++r)
          racc[r][ci] = __builtin_amdgcn_mfma_f32_16x16x32_bf16(A[r], B, racc[r][ci], 0, 0, 0);
      }
    }
    __syncthreads();  // done reading T1s; U2 becomes wvs

    // weighted values -> wvs bf16 [64][512B], swizzle byte ^= ((row>>2)&3)<<5
    #pragma unroll
    for (int ci = 0; ci < 4; ++ci) {
      int cf = 4 * w + ci;  // == head index
      #pragma unroll
      for (int r = 0; r < 4; ++r) {
        #pragma unroll
        for (int j = 0; j < 4; ++j) {
          int row = 16 * r + 4 * (lane >> 4) + j;
          float v = racc[r][ci][j];
          v = v > 0.f ? v : 0.f;
          v *= wl[row * 16 + cf];
          int colb = (16 * cf + (lane & 15)) * 2;
          *(unsigned short*)(U2 + row * 512 + (colb ^ (((row >> 2) & 3) << 5))) = f2bf(v);
        }
      }
    }
    __syncthreads();

    // segment accumulate: wave 0, thread t owns cols 4t..4t+3; exclusive plain stores
    if (tid < 64) {
      for (int v = 0; v < cn; ++v) {
        int g = sl[v];
        if (g != cur_g) {
          if (cur_g >= 0) {
            float4 o; o.x = a0; o.y = a1; o.z = a2; o.w = a3;
            ((float4*)out)[(size_t)cur_g * 64 + tid] = o;
          }
          cur_g = g; a0 = a1 = a2 = a3 = 0.f;
        }
        u16x4 x = *(const u16x4*)(U2 + v * 512 + ((tid * 8) ^ (((v >> 2) & 3) << 5)));
        a0 += bf2f(x[0]); a1 += bf2f(x[1]); a2 += bf2f(x[2]); a3 += bf2f(x[3]);
      }
    }
    __syncthreads();  // before next chunk overwrites U2
  }
  if (tid < 64 && cur_g >= 0) {
    float4 o; o.x = a0; o.y = a1; o.z = a2; o.w = a3;
    ((float4*)out)[(size_t)cur_g * 64 + tid] = o;
  }
}

extern "C" void kernel_launch(void* const* d_in, const int* in_sizes, int n_in,
                              void* d_out, int out_size, void* d_ws, size_t ws_size,
                              hipStream_t stream) {
  (void)in_sizes; (void)n_in; (void)out_size; (void)ws_size;
  const float* X  = (const float*)d_in[0];
  const int* seg  = (const int*)d_in[1];
  const float* s1 = (const float*)d_in[3];
  const float* s2 = (const float*)d_in[4];
  const float* t1 = (const float*)d_in[5];
  const float* t2 = (const float*)d_in[6];
  float* out = (float*)d_out;
  char* ws = (char*)d_ws;

  // ws layout: [0,200704) weight frags bf16; [256K,~460K) offsets; [512K,512K+64M) scores->weights fp32;
  //            [512K+64M, +256M) T1 bf16.  Total ~324 MB.
  unsigned short* WB = (unsigned short*)ws;
  int* off      = (int*)(ws + (1 << 18));
  float* scores = (float*)(ws + (1 << 19));
  unsigned short* T1 = (unsigned short*)(ws + (1 << 19) + ((size_t)1 << 26));

  k_prep<<<392, 256, 0, stream>>>(s1, s2, t1, t2, WB);
  k_offsets<<<196, 256, 0, stream>>>(seg, off);
  k_zero<<<12500, 256, 0, stream>>>(out);
  k_front<<<15625, 256, 0, stream>>>(X, WB, WB + 32768, WB + 98304, scores, T1);
  k_softmax<<<12500, 256, 0, stream>>>(scores, off);
  k_back<<<3907, 256, 0, stream>>>(T1, WB + 65536, scores, seg, off, out);
}

// Round 2
// 868.101 us; speedup vs baseline: 1.2885x; 1.2885x over previous
//
#include <hip/hip_runtime.h>
#include <stdint.h>

#define VN   1000000
#define VDIM 256
#define GDIM 256
#define NH   16
#define NG   50000
#define HIDD 128
#define NTILES 15625   // VN / 64

using bf16x8 = __attribute__((ext_vector_type(8))) __bf16;
using f32x4  = __attribute__((ext_vector_type(4))) float;
using u16x4  = __attribute__((ext_vector_type(4))) unsigned short;
using u16x8  = __attribute__((ext_vector_type(8))) unsigned short;

__device__ __forceinline__ unsigned short f2bf(float f) {
  unsigned u = __float_as_uint(f);
  return (unsigned short)((u + 0x7FFFu + ((u >> 16) & 1u)) >> 16);  // RNE
}
__device__ __forceinline__ float bf2f(unsigned short h) {
  return __uint_as_float(((unsigned)h) << 16);
}
__device__ __forceinline__ f32x4 fzero4() { f32x4 z = {0.f, 0.f, 0.f, 0.f}; return z; }

// ---------------- weight prep: fp32 -> bf16 in MFMA B-fragment order ----------------
// For W[K][N]: frag element idx = ((c*(K/32)+s)*64 + lane)*8 + j  holds W[32s+8*(lane>>4)+j][16c+(lane&15)]
__global__ void k_prep(const float* __restrict__ s1, const float* __restrict__ s2,
                       const float* __restrict__ t1, const float* __restrict__ t2,
                       unsigned short* __restrict__ WB) {
  int t = blockIdx.x * 256 + threadIdx.x;
  const float* W; unsigned short* dst; int K, N, lid;
  if (t < 32768)       { W = s1; dst = WB;          K = 256; N = 128; lid = t; }
  else if (t < 65536)  { W = t1; dst = WB + 32768;  K = 256; N = 128; lid = t - 32768; }
  else if (t < 98304)  { W = t2; dst = WB + 65536;  K = 128; N = 256; lid = t - 65536; }
  else if (t < 100352) { W = s2; dst = WB + 98304;  K = 128; N = 16;  lid = t - 98304; }
  else return;
  int j = lid & 7, l = (lid >> 3) & 63, rem = lid >> 9;
  int KS = K >> 5;
  int s = rem % KS, c = rem / KS;
  int row = 32 * s + 8 * (l >> 4) + j;
  int col = 16 * c + (l & 15);
  dst[lid] = f2bf(W[row * N + col]);
}

// ---------------- graph start offsets (seg is sorted) ----------------
__global__ void k_offsets(const int* __restrict__ seg, int* __restrict__ off) {
  int g = blockIdx.x * 256 + threadIdx.x;
  if (g > NG) return;
  int lo = 0, hi = VN;
  while (lo < hi) { int mid = (lo + hi) >> 1; if (seg[mid] < g) lo = mid + 1; else hi = mid; }
  off[g] = lo;
}

__global__ void k_zero(float* __restrict__ out) {
  int i = blockIdx.x * 256 + threadIdx.x;
  float4 z = make_float4(0.f, 0.f, 0.f, 0.f);
  if (i < NG * GDIM / 4) ((float4*)out)[i] = z;
}

// ---------------- front: X -> scores (fp32) + T1 (raw swizzled bf16 tiles) ----------------
__global__ __launch_bounds__(256) void k_front(
    const float* __restrict__ X,
    const unsigned short* __restrict__ WBs1,
    const unsigned short* __restrict__ WBt1,
    const unsigned short* __restrict__ WBs2,
    float* __restrict__ scores,
    unsigned short* __restrict__ T1out) {
  __shared__ __align__(16) char U[49152];  // [0,32768) Xs (alias Ts) ; [32768,49152) Hs
  char* const Xs = U;
  char* const Hs = U + 32768;
  char* const Ts = U;

  const int tid  = threadIdx.x;
  const int lane = tid & 63;
  const int w    = tid >> 6;
  const size_t base = (size_t)blockIdx.x * 64;

  // stage X tile -> bf16 LDS, rows of 512B, XOR swizzle byte^=((row&7)<<4)
  {
    const float4* Xg = (const float4*)(X + base * VDIM);
    #pragma unroll
    for (int i = 0; i < 16; ++i) {
      int f = tid + 256 * i;
      int row = f >> 6, c4 = f & 63;
      float4 v = Xg[f];
      u16x4 b = { f2bf(v.x), f2bf(v.y), f2bf(v.z), f2bf(v.w) };
      *(u16x4*)(Xs + row * 512 + ((c4 * 8) ^ ((row & 7) << 4))) = b;
    }
  }
  __syncthreads();

  // layer 1: C1[64][256] = relu(X @ [Sw1|Tw1]); waves 0,1 -> Sw1 cols, waves 2,3 -> Tw1 cols
  const unsigned short* WB = (w < 2) ? WBs1 : WBt1;
  const int cbase = (w & 1) * 4;  // col-frags cbase..cbase+3 within the 128-col half
  f32x4 acc[4][4];
  #pragma unroll
  for (int r = 0; r < 4; ++r)
    #pragma unroll
    for (int c = 0; c < 4; ++c) acc[r][c] = fzero4();

  #pragma unroll
  for (int ks = 0; ks < 8; ++ks) {
    bf16x8 A[4];
    #pragma unroll
    for (int r = 0; r < 4; ++r) {
      int row = 16 * r + (lane & 15);
      int cb = 64 * ks + 16 * (lane >> 4);
      A[r] = *(const bf16x8*)(Xs + row * 512 + (cb ^ ((row & 7) << 4)));
    }
    #pragma unroll
    for (int ci = 0; ci < 4; ++ci) {
      bf16x8 B = *(const bf16x8*)(WB + (size_t)(((cbase + ci) * 8 + ks) * 64 + lane) * 8);
      #pragma unroll
      for (int r = 0; r < 4; ++r)
        acc[r][ci] = __builtin_amdgcn_mfma_f32_16x16x32_bf16(A[r], B, acc[r][ci], 0, 0, 0);
    }
  }
  __syncthreads();  // everyone done reading Xs

  // write C1: relu + bf16. waves 0-1 -> Hs (H1), waves 2-3 -> Ts (T1), [64][128] 256B rows
  {
    char* const dst = (w < 2) ? Hs : Ts;
    #pragma unroll
    for (int ci = 0; ci < 4; ++ci) {
      int colf = cbase + ci;
      #pragma unroll
      for (int r = 0; r < 4; ++r) {
        #pragma unroll
        for (int j = 0; j < 4; ++j) {
          int row = 16 * r + 4 * (lane >> 4) + j;
          int col = 16 * colf + (lane & 15);
          float v = acc[r][ci][j];
          v = v > 0.f ? v : 0.f;
          *(unsigned short*)(dst + row * 256 + ((col * 2) ^ ((row & 7) << 4))) = f2bf(v);
        }
      }
    }
  }
  __syncthreads();

  // T1 tile -> global as RAW swizzled bytes (k_back restages it verbatim)
  {
    #pragma unroll
    for (int i = 0; i < 4; ++i) {
      int f = tid + 256 * i;           // 1024 chunks of 16B
      u16x8 v = *(const u16x8*)(Ts + f * 16);
      *(u16x8*)(T1out + base * HIDD + (size_t)f * 8) = v;
    }
  }

  // scores = H1 @ Sw2 : wave w -> row-frag w
  {
    f32x4 sa = fzero4();
    #pragma unroll
    for (int ks = 0; ks < 4; ++ks) {
      int row = 16 * w + (lane & 15);
      int cb = 64 * ks + 16 * (lane >> 4);
      bf16x8 A2 = *(const bf16x8*)(Hs + row * 256 + (cb ^ ((row & 7) << 4)));
      bf16x8 B2 = *(const bf16x8*)(WBs2 + (size_t)(ks * 64 + lane) * 8);
      sa = __builtin_amdgcn_mfma_f32_16x16x32_bf16(A2, B2, sa, 0, 0, 0);
    }
    #pragma unroll
    for (int j = 0; j < 4; ++j) {
      int row = 16 * w + 4 * (lane >> 4) + j;
      scores[(base + row) * NH + (lane & 15)] = sa[j];
    }
  }
}

// ---------------- segment softmax, in place: scores -> weights ----------------
__global__ void k_softmax(float* __restrict__ sc, const int* __restrict__ off) {
  int g = blockIdx.x * 4 + (threadIdx.x >> 6);
  int lane = threadIdx.x & 63;
  if (g >= NG) return;
  int o0 = off[g], o1 = off[g + 1];
  int n = o1 - o0;
  if (n <= 0) return;
  int h = lane & 15, sl = lane >> 4;   // 16 heads x 4 node-slices per wave
  float m = -3.4e38f;
  for (int i = sl; i < n; i += 4) m = fmaxf(m, sc[(size_t)(o0 + i) * NH + h]);
  m = fmaxf(m, __shfl_xor(m, 16, 64));
  m = fmaxf(m, __shfl_xor(m, 32, 64));
  float s = 0.f;
  for (int i = sl; i < n; i += 4) s += __expf(sc[(size_t)(o0 + i) * NH + h] - m);
  s += __shfl_xor(s, 16, 64);
  s += __shfl_xor(s, 32, 64);
  float rs = 1.0f / s;
  for (int i = sl; i < n; i += 4) {
    size_t idx = (size_t)(o0 + i) * NH + h;
    sc[idx] = __expf(sc[idx] - m) * rs;
  }
}

// ---------------- back: T1 -> relu(T1@Tw2) * weights -> segment sum (atomic flush) ----------------
__global__ __launch_bounds__(256) void k_back(
    const unsigned short* __restrict__ T1,    // [NTILES][8192] shorts, raw swizzled tiles
    const unsigned short* __restrict__ WBt2,
    const float* __restrict__ wgt,
    const int* __restrict__ seg,
    float* __restrict__ out) {
  __shared__ __align__(16) char U2[32768];  // T1s [0,16384) aliased by WV [0,32768)
  __shared__ float wl[64 * 16];
  __shared__ int sl[64];

  const int tid  = threadIdx.x;
  const int lane = tid & 63;
  const int w    = tid >> 6;

  const int t0 = blockIdx.x * 4;
  const int nt = (NTILES - t0 < 4) ? (NTILES - t0) : 4;

  // hoist Tw2 B-fragments: wave w owns col-frags 4w..4w+3 (loop-invariant)
  bf16x8 Bf[4][4];
  #pragma unroll
  for (int ci = 0; ci < 4; ++ci) {
    int cf = 4 * w + ci;
    #pragma unroll
    for (int ks = 0; ks < 4; ++ks)
      Bf[ci][ks] = *(const bf16x8*)(WBt2 + (size_t)((cf * 4 + ks) * 64 + lane) * 8);
  }

  float acc = 0.f;       // thread owns output column `tid`
  int cur_g = -1;

  for (int t = t0; t < t0 + nt; ++t) {
    const int cb = t * 64;
    // stage raw swizzled T1 tile: pure linear 16KB copy
    #pragma unroll
    for (int i = 0; i < 4; ++i) {
      int f = tid + 256 * i;
      *(u16x8*)(U2 + f * 16) = *(const u16x8*)(T1 + (size_t)t * 8192 + (size_t)f * 8);
    }
    // stage weights [64][16] and seg ids
    #pragma unroll
    for (int i = 0; i < 4; ++i) {
      int f = tid + 256 * i;
      wl[f] = wgt[(size_t)cb * NH + f];
    }
    if (tid < 64) sl[tid] = seg[cb + tid];
    __syncthreads();

    // R = relu(T1s @ Tw2); wave w -> col-frags 4w..4w+3
    f32x4 racc[4][4];
    #pragma unroll
    for (int r = 0; r < 4; ++r)
      #pragma unroll
      for (int c = 0; c < 4; ++c) racc[r][c] = fzero4();
    #pragma unroll
    for (int ks = 0; ks < 4; ++ks) {
      bf16x8 A[4];
      #pragma unroll
      for (int r = 0; r < 4; ++r) {
        int row = 16 * r + (lane & 15);
        int cbyte = 64 * ks + 16 * (lane >> 4);
        A[r] = *(const bf16x8*)(U2 + row * 256 + (cbyte ^ ((row & 7) << 4)));
      }
      #pragma unroll
      for (int ci = 0; ci < 4; ++ci) {
        #pragma unroll
        for (int r = 0; r < 4; ++r)
          racc[r][ci] = __builtin_amdgcn_mfma_f32_16x16x32_bf16(A[r], Bf[ci][ks], racc[r][ci], 0, 0, 0);
      }
    }
    __syncthreads();  // done reading T1s; U2 becomes WV

    // weighted values -> WV bf16 [64][512B], swizzle byte ^= ((row>>2)&3)<<5
    #pragma unroll
    for (int ci = 0; ci < 4; ++ci) {
      int cf = 4 * w + ci;  // == head index
      #pragma unroll
      for (int r = 0; r < 4; ++r) {
        #pragma unroll
        for (int j = 0; j < 4; ++j) {
          int row = 16 * r + 4 * (lane >> 4) + j;
          float v = racc[r][ci][j];
          v = v > 0.f ? v : 0.f;
          v *= wl[row * 16 + cf];
          int colb = (16 * cf + (lane & 15)) * 2;
          *(unsigned short*)(U2 + row * 512 + (colb ^ (((row >> 2) & 3) << 5))) = f2bf(v);
        }
      }
    }
    __syncthreads();

    // segment accumulate: all 256 threads, thread owns column tid; uniform scalar branch
    for (int v = 0; v < 64; ++v) {
      int g = __builtin_amdgcn_readfirstlane(sl[v]);
      if (g != cur_g) {
        if (cur_g >= 0) atomicAdd(out + (size_t)cur_g * GDIM + tid, acc);
        cur_g = g; acc = 0.f;
      }
      acc += bf2f(*(const unsigned short*)(U2 + v * 512 + ((tid * 2) ^ (((v >> 2) & 3) << 5))));
    }
    __syncthreads();  // before next chunk overwrites U2
  }
  if (cur_g >= 0) atomicAdd(out + (size_t)cur_g * GDIM + tid, acc);
}

extern "C" void kernel_launch(void* const* d_in, const int* in_sizes, int n_in,
                              void* d_out, int out_size, void* d_ws, size_t ws_size,
                              hipStream_t stream) {
  (void)in_sizes; (void)n_in; (void)out_size; (void)ws_size;
  const float* X  = (const float*)d_in[0];
  const int* seg  = (const int*)d_in[1];
  const float* s1 = (const float*)d_in[3];
  const float* s2 = (const float*)d_in[4];
  const float* t1 = (const float*)d_in[5];
  const float* t2 = (const float*)d_in[6];
  float* out = (float*)d_out;
  char* ws = (char*)d_ws;

  // ws layout: [0,200704) weight frags bf16; [256K,~460K) offsets; [512K,512K+64M) scores->weights fp32;
  //            [512K+64M, +256M) T1 bf16.  Total ~324 MB.
  unsigned short* WB = (unsigned short*)ws;
  int* off      = (int*)(ws + (1 << 18));
  float* scores = (float*)(ws + (1 << 19));
  unsigned short* T1 = (unsigned short*)(ws + (1 << 19) + ((size_t)1 << 26));

  k_prep<<<392, 256, 0, stream>>>(s1, s2, t1, t2, WB);
  k_offsets<<<196, 256, 0, stream>>>(seg, off);
  k_zero<<<12500, 256, 0, stream>>>(out);
  k_front<<<15625, 256, 0, stream>>>(X, WB, WB + 32768, WB + 98304, scores, T1);
  k_softmax<<<12500, 256, 0, stream>>>(scores, off);
  k_back<<<3907, 256, 0, stream>>>(T1, WB + 65536, scores, seg, out);
}

// Round 3
// 568.237 us; speedup vs baseline: 1.9684x; 1.5277x over previous
//
#include <hip/hip_runtime.h>
#include <stdint.h>

#define VN   1000000
#define VDIM 256
#define GDIM 256
#define NH   16
#define NG   50000
#define HIDD 128
#define NTILES 15625   // VN / 64
#define TPB_TILES 5    // 15625 = 5 * 3125, no remainder

using bf16x8 = __attribute__((ext_vector_type(8))) __bf16;
using f32x4  = __attribute__((ext_vector_type(4))) float;
using u16x4  = __attribute__((ext_vector_type(4))) unsigned short;
using u16x8  = __attribute__((ext_vector_type(8))) unsigned short;

__device__ __forceinline__ unsigned short f2bf(float f) {
  unsigned u = __float_as_uint(f);
  return (unsigned short)((u + 0x7FFFu + ((u >> 16) & 1u)) >> 16);  // RNE
}
__device__ __forceinline__ float bf2f(unsigned short h) {
  return __uint_as_float(((unsigned)h) << 16);
}
__device__ __forceinline__ f32x4 fzero4() { f32x4 z = {0.f, 0.f, 0.f, 0.f}; return z; }

// async global->LDS, 16B per lane; LDS dest is wave-uniform base + lane*16 (HW scatter)
typedef __attribute__((address_space(1))) const void* gas_t;
typedef __attribute__((address_space(3))) void* las_t;
__device__ __forceinline__ void gld16(const void* g, void* l) {
  __builtin_amdgcn_global_load_lds((gas_t)g, (las_t)l, 16, 0, 0);
}

// ---------------- weight prep: fp32 -> bf16 in MFMA B-fragment order ----------------
// For W[K][N]: frag element idx = ((c*(K/32)+s)*64 + lane)*8 + j  holds W[32s+8*(lane>>4)+j][16c+(lane&15)]
__global__ void k_prep(const float* __restrict__ s1, const float* __restrict__ s2,
                       const float* __restrict__ t1, const float* __restrict__ t2,
                       unsigned short* __restrict__ WB) {
  int t = blockIdx.x * 256 + threadIdx.x;
  const float* W; unsigned short* dst; int K, N, lid;
  if (t < 32768)       { W = s1; dst = WB;          K = 256; N = 128; lid = t; }
  else if (t < 65536)  { W = t1; dst = WB + 32768;  K = 256; N = 128; lid = t - 32768; }
  else if (t < 98304)  { W = t2; dst = WB + 65536;  K = 128; N = 256; lid = t - 65536; }
  else if (t < 100352) { W = s2; dst = WB + 98304;  K = 128; N = 16;  lid = t - 98304; }
  else return;
  int j = lid & 7, l = (lid >> 3) & 63, rem = lid >> 9;
  int KS = K >> 5;
  int s = rem % KS, c = rem / KS;
  int row = 32 * s + 8 * (l >> 4) + j;
  int col = 16 * c + (l & 15);
  dst[lid] = f2bf(W[row * N + col]);
}

// ---------------- graph start offsets (seg is sorted) ----------------
__global__ void k_offsets(const int* __restrict__ seg, int* __restrict__ off) {
  int g = blockIdx.x * 256 + threadIdx.x;
  if (g > NG) return;
  int lo = 0, hi = VN;
  while (lo < hi) { int mid = (lo + hi) >> 1; if (seg[mid] < g) lo = mid + 1; else hi = mid; }
  off[g] = lo;
}

__global__ void k_zero(float* __restrict__ out) {
  int i = blockIdx.x * 256 + threadIdx.x;
  float4 z = make_float4(0.f, 0.f, 0.f, 0.f);
  if (i < NG * GDIM / 4) ((float4*)out)[i] = z;
}

// ---------------- front: X -> scores (fp32) + T1 (raw swizzled bf16 tiles) ----------------
__global__ __launch_bounds__(256) void k_front(
    const float* __restrict__ X,
    const unsigned short* __restrict__ WBs1,
    const unsigned short* __restrict__ WBt1,
    const unsigned short* __restrict__ WBs2,
    float* __restrict__ scores,
    unsigned short* __restrict__ T1out) {
  __shared__ __align__(16) char U[49152];  // [0,32768) Xs (alias Ts) ; [32768,49152) Hs
  char* const Xs = U;
  char* const Hs = U + 32768;
  char* const Ts = U;

  const int tid  = threadIdx.x;
  const int lane = tid & 63;
  const int w    = tid >> 6;
  const size_t base = (size_t)blockIdx.x * 64;

  // stage X tile -> bf16 LDS, rows of 512B, XOR swizzle byte^=((row&7)<<4)
  {
    const float4* Xg = (const float4*)(X + base * VDIM);
    #pragma unroll
    for (int i = 0; i < 16; ++i) {
      int f = tid + 256 * i;
      int row = f >> 6, c4 = f & 63;
      float4 v = Xg[f];
      u16x4 b = { f2bf(v.x), f2bf(v.y), f2bf(v.z), f2bf(v.w) };
      *(u16x4*)(Xs + row * 512 + ((c4 * 8) ^ ((row & 7) << 4))) = b;
    }
  }
  __syncthreads();

  // layer 1: C1[64][256] = relu(X @ [Sw1|Tw1]); waves 0,1 -> Sw1 cols, waves 2,3 -> Tw1 cols
  const unsigned short* WB = (w < 2) ? WBs1 : WBt1;
  const int cbase = (w & 1) * 4;  // col-frags cbase..cbase+3 within the 128-col half
  f32x4 acc[4][4];
  #pragma unroll
  for (int r = 0; r < 4; ++r)
    #pragma unroll
    for (int c = 0; c < 4; ++c) acc[r][c] = fzero4();

  #pragma unroll
  for (int ks = 0; ks < 8; ++ks) {
    bf16x8 A[4];
    #pragma unroll
    for (int r = 0; r < 4; ++r) {
      int row = 16 * r + (lane & 15);
      int cb = 64 * ks + 16 * (lane >> 4);
      A[r] = *(const bf16x8*)(Xs + row * 512 + (cb ^ ((row & 7) << 4)));
    }
    #pragma unroll
    for (int ci = 0; ci < 4; ++ci) {
      bf16x8 B = *(const bf16x8*)(WB + (size_t)(((cbase + ci) * 8 + ks) * 64 + lane) * 8);
      #pragma unroll
      for (int r = 0; r < 4; ++r)
        acc[r][ci] = __builtin_amdgcn_mfma_f32_16x16x32_bf16(A[r], B, acc[r][ci], 0, 0, 0);
    }
  }
  __syncthreads();  // everyone done reading Xs

  // write C1: relu + bf16. waves 0-1 -> Hs (H1), waves 2-3 -> Ts (T1), [64][128] 256B rows
  {
    char* const dst = (w < 2) ? Hs : Ts;
    #pragma unroll
    for (int ci = 0; ci < 4; ++ci) {
      int colf = cbase + ci;
      #pragma unroll
      for (int r = 0; r < 4; ++r) {
        #pragma unroll
        for (int j = 0; j < 4; ++j) {
          int row = 16 * r + 4 * (lane >> 4) + j;
          int col = 16 * colf + (lane & 15);
          float v = acc[r][ci][j];
          v = v > 0.f ? v : 0.f;
          *(unsigned short*)(dst + row * 256 + ((col * 2) ^ ((row & 7) << 4))) = f2bf(v);
        }
      }
    }
  }
  __syncthreads();

  // T1 tile -> global as RAW swizzled bytes (k_back restages it verbatim via global_load_lds)
  {
    #pragma unroll
    for (int i = 0; i < 4; ++i) {
      int f = tid + 256 * i;           // 1024 chunks of 16B
      u16x8 v = *(const u16x8*)(Ts + f * 16);
      *(u16x8*)(T1out + base * HIDD + (size_t)f * 8) = v;
    }
  }

  // scores = H1 @ Sw2 : wave w -> row-frag w
  {
    f32x4 sa = fzero4();
    #pragma unroll
    for (int ks = 0; ks < 4; ++ks) {
      int row = 16 * w + (lane & 15);
      int cb = 64 * ks + 16 * (lane >> 4);
      bf16x8 A2 = *(const bf16x8*)(Hs + row * 256 + (cb ^ ((row & 7) << 4)));
      bf16x8 B2 = *(const bf16x8*)(WBs2 + (size_t)(ks * 64 + lane) * 8);
      sa = __builtin_amdgcn_mfma_f32_16x16x32_bf16(A2, B2, sa, 0, 0, 0);
    }
    #pragma unroll
    for (int j = 0; j < 4; ++j) {
      int row = 16 * w + 4 * (lane >> 4) + j;
      scores[(base + row) * NH + (lane & 15)] = sa[j];
    }
  }
}

// ---------------- segment softmax, in place: scores -> weights ----------------
__global__ void k_softmax(float* __restrict__ sc, const int* __restrict__ off) {
  int g = blockIdx.x * 4 + (threadIdx.x >> 6);
  int lane = threadIdx.x & 63;
  if (g >= NG) return;
  int o0 = off[g], o1 = off[g + 1];
  int n = o1 - o0;
  if (n <= 0) return;
  int h = lane & 15, sl = lane >> 4;   // 16 heads x 4 node-slices per wave
  float m = -3.4e38f;
  for (int i = sl; i < n; i += 4) m = fmaxf(m, sc[(size_t)(o0 + i) * NH + h]);
  m = fmaxf(m, __shfl_xor(m, 16, 64));
  m = fmaxf(m, __shfl_xor(m, 32, 64));
  float s = 0.f;
  for (int i = sl; i < n; i += 4) s += __expf(sc[(size_t)(o0 + i) * NH + h] - m);
  s += __shfl_xor(s, 16, 64);
  s += __shfl_xor(s, 32, 64);
  float rs = 1.0f / s;
  for (int i = sl; i < n; i += 4) {
    size_t idx = (size_t)(o0 + i) * NH + h;
    sc[idx] = __expf(sc[idx] - m) * rs;
  }
}

// ---------------- back: T1 -> relu(T1@Tw2) * weights -> segment sum (in-register) ----------------
// LDS layout (bytes): T1 dbuf [0,16384)+[16384,32768); wl dbuf [32768,36864)+[36864,40960);
//                     sl int[320] at [40960, 42240)
__global__ __launch_bounds__(256, 3) void k_back(
    const unsigned short* __restrict__ T1,    // [NTILES][8192] shorts, raw swizzled tiles
    const unsigned short* __restrict__ WBt2,
    const float* __restrict__ wgt,
    const int* __restrict__ seg,
    float* __restrict__ out) {
  __shared__ __align__(16) char U2[42240];

  const int tid  = threadIdx.x;
  const int lane = tid & 63;
  const int w    = tid >> 6;
  const int lg   = lane >> 4;
  const int t0   = blockIdx.x * TPB_TILES;

  // hoist Tw2 B-fragments FIRST (oldest vmem => compiler waits them without draining prefetch)
  bf16x8 Bf[4][4];
  #pragma unroll
  for (int ci = 0; ci < 4; ++ci)
    #pragma unroll
    for (int ks = 0; ks < 4; ++ks)
      Bf[ci][ks] = *(const bf16x8*)(WBt2 + (size_t)(((4 * w + ci) * 4 + ks) * 64 + lane) * 8);

  // stage seg ids for all 5 tiles -> sl (lgkm)
  {
    int* sl = (int*)(U2 + 40960);
    sl[tid] = seg[t0 * 64 + tid];
    if (tid < 64) sl[256 + tid] = seg[t0 * 64 + 256 + tid];
  }

  // async stage helper: T1 tile (16KB) + weights (4KB), 5 glds per wave
  auto stage = [&](int t, int buf) {
    const char* gsrc = (const char*)(T1 + (size_t)t * 8192);
    char* ldst = U2 + buf * 16384;
    #pragma unroll
    for (int i = 0; i < 4; ++i) {
      int off = (w * 64 + i * 256) * 16;          // wave-uniform LDS base; HW adds lane*16
      gld16(gsrc + off + lane * 16, ldst + off);
    }
    const char* gw = (const char*)(wgt + (size_t)t * 64 * NH);
    gld16(gw + w * 1024 + lane * 16, U2 + 32768 + buf * 4096 + w * 1024);
  };

  stage(t0, 0);  // prologue

  for (int it = 0; it < TPB_TILES; ++it) {
    const int buf = it & 1;
    if (it + 1 < TPB_TILES) {
      stage(t0 + it + 1, buf ^ 1);
      asm volatile("s_waitcnt vmcnt(5) lgkmcnt(0)" ::: "memory");   // tile it staged, tile it+1 in flight
    } else {
      asm volatile("s_waitcnt vmcnt(0) lgkmcnt(0)" ::: "memory");
    }
    __builtin_amdgcn_sched_barrier(0);
    __builtin_amdgcn_s_barrier();

    // per-lane graph id for this tile's 64 rows
    const int gv = ((const int*)(U2 + 40960))[it * 64 + lane];
    const int gp = __shfl_up(gv, 1, 64);
    const unsigned long long bmask = __ballot(gv != gp) | 1ull;  // segment-start rows

    // R = T1s @ Tw2 ; wave w -> col-frags 4w..4w+3
    const char* Tb = U2 + buf * 16384;
    f32x4 racc[4][4];
    #pragma unroll
    for (int r = 0; r < 4; ++r)
      #pragma unroll
      for (int c = 0; c < 4; ++c) racc[r][c] = fzero4();
    #pragma unroll
    for (int ks = 0; ks < 4; ++ks) {
      bf16x8 A[4];
      #pragma unroll
      for (int r = 0; r < 4; ++r) {
        int row = 16 * r + (lane & 15);
        int cbyte = 64 * ks + 16 * (lane >> 4);
        A[r] = *(const bf16x8*)(Tb + row * 256 + (cbyte ^ ((row & 7) << 4)));
      }
      #pragma unroll
      for (int ci = 0; ci < 4; ++ci)
        #pragma unroll
        for (int r = 0; r < 4; ++r)
          racc[r][ci] = __builtin_amdgcn_mfma_f32_16x16x32_bf16(A[r], Bf[ci][ks], racc[r][ci], 0, 0, 0);
    }

    // relu + per-head weight multiply, in place (racc -> weighted values)
    const char* Wb = U2 + 32768 + buf * 4096;
    #pragma unroll
    for (int r = 0; r < 4; ++r)
      #pragma unroll
      for (int j = 0; j < 4; ++j) {
        int row = 16 * r + 4 * lg + j;
        f32x4 wr = *(const f32x4*)(Wb + row * 64 + w * 16);   // heads 4w..4w+3, broadcast across 16 lanes
        #pragma unroll
        for (int ci = 0; ci < 4; ++ci) {
          float v = racc[r][ci][j];
          v = v > 0.f ? v : 0.f;
          racc[r][ci][j] = v * wr[ci];
        }
      }

    // in-register segmented column sums; interior segments -> plain store, edge -> atomic
    unsigned long long m = bmask;
    while (m) {
      int a = __builtin_ctzll(m);
      m &= m - 1;
      int b = m ? __builtin_ctzll(m) : 64;
      int g = __shfl(gv, a, 64);
      f32x4 s = fzero4();
      #pragma unroll
      for (int r = 0; r < 4; ++r)
        #pragma unroll
        for (int j = 0; j < 4; ++j) {
          int row = 16 * r + 4 * lg + j;
          float msk = ((unsigned)(row - a) < (unsigned)(b - a)) ? 1.f : 0.f;
          #pragma unroll
          for (int ci = 0; ci < 4; ++ci) s[ci] = fmaf(msk, racc[r][ci][j], s[ci]);
        }
      #pragma unroll
      for (int ci = 0; ci < 4; ++ci) {
        s[ci] += __shfl_xor(s[ci], 16, 64);
        s[ci] += __shfl_xor(s[ci], 32, 64);
      }
      bool edge = (a == 0) || (b == 64);
      if (lane < 16) {
        float* dst = out + (size_t)g * GDIM + 64 * w + lane;
        if (edge) {
          atomicAdd(dst,      s[0]); atomicAdd(dst + 16, s[1]);
          atomicAdd(dst + 32, s[2]); atomicAdd(dst + 48, s[3]);
        } else {
          dst[0] = s[0]; dst[16] = s[1]; dst[32] = s[2]; dst[48] = s[3];
        }
      }
    }

    asm volatile("s_waitcnt lgkmcnt(0)" ::: "memory");
    __builtin_amdgcn_s_barrier();       // all reads of buf done before it+1's prefetch target reuse
    __builtin_amdgcn_sched_barrier(0);
  }
}

extern "C" void kernel_launch(void* const* d_in, const int* in_sizes, int n_in,
                              void* d_out, int out_size, void* d_ws, size_t ws_size,
                              hipStream_t stream) {
  (void)in_sizes; (void)n_in; (void)out_size; (void)ws_size;
  const float* X  = (const float*)d_in[0];
  const int* seg  = (const int*)d_in[1];
  const float* s1 = (const float*)d_in[3];
  const float* s2 = (const float*)d_in[4];
  const float* t1 = (const float*)d_in[5];
  const float* t2 = (const float*)d_in[6];
  float* out = (float*)d_out;
  char* ws = (char*)d_ws;

  // ws layout: [0,200704) weight frags bf16; [256K,~460K) offsets; [512K,512K+64M) scores->weights fp32;
  //            [512K+64M, +256M) T1 bf16.  Total ~324 MB.
  unsigned short* WB = (unsigned short*)ws;
  int* off      = (int*)(ws + (1 << 18));
  float* scores = (float*)(ws + (1 << 19));
  unsigned short* T1 = (unsigned short*)(ws + (1 << 19) + ((size_t)1 << 26));

  k_prep<<<392, 256, 0, stream>>>(s1, s2, t1, t2, WB);
  k_offsets<<<196, 256, 0, stream>>>(seg, off);
  k_zero<<<12500, 256, 0, stream>>>(out);
  k_front<<<15625, 256, 0, stream>>>(X, WB, WB + 32768, WB + 98304, scores, T1);
  k_softmax<<<12500, 256, 0, stream>>>(scores, off);
  k_back<<<3125, 256, 0, stream>>>(T1, WB + 65536, scores, seg, out);
}

// Round 4
// 516.557 us; speedup vs baseline: 2.1654x; 1.1000x over previous
//
#include <hip/hip_runtime.h>
#include <stdint.h>

#define VN   1000000
#define VDIM 256
#define GDIM 256
#define NH   16
#define NG   50000
#define HIDD 128
#define NTILES 15625   // VN / 64

using bf16x8 = __attribute__((ext_vector_type(8))) __bf16;
using f32x4  = __attribute__((ext_vector_type(4))) float;
using u16x4  = __attribute__((ext_vector_type(4))) unsigned short;
using u16x8  = __attribute__((ext_vector_type(8))) unsigned short;

__device__ __forceinline__ unsigned short f2bf(float f) {
  unsigned u = __float_as_uint(f);
  return (unsigned short)((u + 0x7FFFu + ((u >> 16) & 1u)) >> 16);  // RNE
}
__device__ __forceinline__ f32x4 fzero4() { f32x4 z = {0.f, 0.f, 0.f, 0.f}; return z; }

// ---------------- weight prep: fp32 -> bf16 in MFMA B-fragment order ----------------
// For W[K][N]: frag element idx = ((c*(K/32)+s)*64 + lane)*8 + j  holds W[32s+8*(lane>>4)+j][16c+(lane&15)]
__global__ void k_prep(const float* __restrict__ s1, const float* __restrict__ s2,
                       const float* __restrict__ t1, const float* __restrict__ t2,
                       unsigned short* __restrict__ WB) {
  int t = blockIdx.x * 256 + threadIdx.x;
  const float* W; unsigned short* dst; int K, N, lid;
  if (t < 32768)       { W = s1; dst = WB;          K = 256; N = 128; lid = t; }
  else if (t < 65536)  { W = t1; dst = WB + 32768;  K = 256; N = 128; lid = t - 32768; }
  else if (t < 98304)  { W = t2; dst = WB + 65536;  K = 128; N = 256; lid = t - 65536; }
  else if (t < 100352) { W = s2; dst = WB + 98304;  K = 128; N = 16;  lid = t - 98304; }
  else return;
  int j = lid & 7, l = (lid >> 3) & 63, rem = lid >> 9;
  int KS = K >> 5;
  int s = rem % KS, c = rem / KS;
  int row = 32 * s + 8 * (l >> 4) + j;
  int col = 16 * c + (l & 15);
  dst[lid] = f2bf(W[row * N + col]);
}

// ---------------- zero: out [NG*GDIM] + denom [NG*NH] ----------------
__global__ void k_zero(float* __restrict__ out, float* __restrict__ denom) {
  int i = blockIdx.x * 256 + threadIdx.x;
  float4 z = make_float4(0.f, 0.f, 0.f, 0.f);
  if (i < NG * GDIM / 4) ((float4*)out)[i] = z;
  int j = i - NG * GDIM / 4;
  if (j >= 0 && j < NG * NH / 4) ((float4*)denom)[j] = z;
}

// ---------------- fused main: X -> layer1 -> {ex/denom, layer2 -> weighted segsum} ----------------
// LDS (64 KB): Xs [0,32768) (exs f32[64][16] aliases [0,4096) after layer-1 reads end);
//              Hs [32768,49152); Ts [49152,65536)
__global__ __launch_bounds__(256) void k_main(
    const float* __restrict__ X,
    const unsigned short* __restrict__ WBs1,
    const unsigned short* __restrict__ WBt1,
    const unsigned short* __restrict__ WBs2,
    const unsigned short* __restrict__ WBt2,
    const int* __restrict__ seg,
    float* __restrict__ denom,
    float* __restrict__ out) {
  __shared__ __align__(16) char U[65536];
  char* const Xs = U;
  char* const Hs = U + 32768;
  char* const Ts = U + 49152;
  float* const exs = (float*)U;          // aliases Xs after layer-1 (safe: post-sync)

  const int tid  = threadIdx.x;
  const int lane = tid & 63;
  const int w    = tid >> 6;
  const int lg   = lane >> 4;
  const size_t base = (size_t)blockIdx.x * 64;

  // per-lane graph id for the tile's 64 rows (lane <-> row)
  const int gv = seg[base + lane];
  const int gp = __shfl_up(gv, 1, 64);
  const unsigned long long bmask = __ballot(gv != gp) | 1ull;  // segment-start rows

  // ---- Phase A: stage X tile -> bf16 LDS, 512B rows, swizzle byte^=((row&7)<<4)
  {
    const float4* Xg = (const float4*)(X + base * VDIM);
    #pragma unroll
    for (int i = 0; i < 16; ++i) {
      int f = tid + 256 * i;
      int row = f >> 6, c4 = f & 63;
      float4 v = Xg[f];
      u16x4 b = { f2bf(v.x), f2bf(v.y), f2bf(v.z), f2bf(v.w) };
      *(u16x4*)(Xs + row * 512 + ((c4 * 8) ^ ((row & 7) << 4))) = b;
    }
  }
  __syncthreads();

  // ---- Phase B: layer 1: C1[64][256] = relu(X @ [Sw1|Tw1]); waves 0,1 -> Sw1, 2,3 -> Tw1
  {
    const unsigned short* WB = (w < 2) ? WBs1 : WBt1;
    const int cbase = (w & 1) * 4;
    f32x4 acc[4][4];
    #pragma unroll
    for (int r = 0; r < 4; ++r)
      #pragma unroll
      for (int c = 0; c < 4; ++c) acc[r][c] = fzero4();

    #pragma unroll
    for (int ks = 0; ks < 8; ++ks) {
      bf16x8 A[4];
      #pragma unroll
      for (int r = 0; r < 4; ++r) {
        int row = 16 * r + (lane & 15);
        int cb = 64 * ks + 16 * (lane >> 4);
        A[r] = *(const bf16x8*)(Xs + row * 512 + (cb ^ ((row & 7) << 4)));
      }
      #pragma unroll
      for (int ci = 0; ci < 4; ++ci) {
        bf16x8 B = *(const bf16x8*)(WB + (size_t)(((cbase + ci) * 8 + ks) * 64 + lane) * 8);
        #pragma unroll
        for (int r = 0; r < 4; ++r)
          acc[r][ci] = __builtin_amdgcn_mfma_f32_16x16x32_bf16(A[r], B, acc[r][ci], 0, 0, 0);
      }
    }

    // relu + bf16 -> Hs (waves 0,1) / Ts (waves 2,3), [64][128] 256B rows, swizzled
    char* const dst = (w < 2) ? Hs : Ts;
    #pragma unroll
    for (int ci = 0; ci < 4; ++ci) {
      int colf = cbase + ci;
      #pragma unroll
      for (int r = 0; r < 4; ++r) {
        #pragma unroll
        for (int j = 0; j < 4; ++j) {
          int row = 16 * r + 4 * (lane >> 4) + j;
          int col = 16 * colf + (lane & 15);
          float v = acc[r][ci][j];
          v = v > 0.f ? v : 0.f;
          *(unsigned short*)(dst + row * 256 + ((col * 2) ^ ((row & 7) << 4))) = f2bf(v);
        }
      }
    }
  }
  __syncthreads();   // all layer-1 reads of Xs done (exs alias safe); Hs/Ts complete

  // ---- Phase C1: scores = H1 @ Sw2 (wave w -> rows 16w..16w+15); ex -> exs + denom atomics
  {
    f32x4 sa = fzero4();
    #pragma unroll
    for (int ks = 0; ks < 4; ++ks) {
      int row = 16 * w + (lane & 15);
      int cb = 64 * ks + 16 * (lane >> 4);
      bf16x8 A2 = *(const bf16x8*)(Hs + row * 256 + (cb ^ ((row & 7) << 4)));
      bf16x8 B2 = *(const bf16x8*)(WBs2 + (size_t)(ks * 64 + lane) * 8);
      sa = __builtin_amdgcn_mfma_f32_16x16x32_bf16(A2, B2, sa, 0, 0, 0);
    }
    const int h = lane & 15;
    const int rowbase = 16 * w + 4 * lg;
    float ex[4]; int gs[4];
    #pragma unroll
    for (int j = 0; j < 4; ++j) {
      ex[j] = __expf(sa[j]);                       // |score| ~< 1.5: no max-subtract needed
      gs[j] = __shfl(gv, rowbase + j, 64);
      exs[(rowbase + j) * 16 + h] = ex[j];
    }
    // run-length compressed denom atomics over this lane's 4 consecutive rows
    float accd = ex[0]; int gcur = gs[0];
    #pragma unroll
    for (int j = 1; j < 4; ++j) {
      if (gs[j] == gcur) accd += ex[j];
      else { atomicAdd(denom + (size_t)gcur * NH + h, accd); gcur = gs[j]; accd = ex[j]; }
    }
    atomicAdd(denom + (size_t)gcur * NH + h, accd);
  }

  // ---- Phase C2: R = T1 @ Tw2 ; wave w -> col-frags 4w..4w+3
  f32x4 racc[4][4];
  #pragma unroll
  for (int r = 0; r < 4; ++r)
    #pragma unroll
    for (int c = 0; c < 4; ++c) racc[r][c] = fzero4();
  #pragma unroll
  for (int ks = 0; ks < 4; ++ks) {
    bf16x8 A[4];
    #pragma unroll
    for (int r = 0; r < 4; ++r) {
      int row = 16 * r + (lane & 15);
      int cbyte = 64 * ks + 16 * (lane >> 4);
      A[r] = *(const bf16x8*)(Ts + row * 256 + (cbyte ^ ((row & 7) << 4)));
    }
    #pragma unroll
    for (int ci = 0; ci < 4; ++ci) {
      bf16x8 B = *(const bf16x8*)(WBt2 + (size_t)(((4 * w + ci) * 4 + ks) * 64 + lane) * 8);
      #pragma unroll
      for (int r = 0; r < 4; ++r)
        racc[r][ci] = __builtin_amdgcn_mfma_f32_16x16x32_bf16(A[r], B, racc[r][ci], 0, 0, 0);
    }
  }
  __syncthreads();   // exs fully written by all waves

  // ---- Phase D: racc = relu(racc) * ex[row][head]  (heads 4w..4w+3 via exs f32x4)
  #pragma unroll
  for (int r = 0; r < 4; ++r)
    #pragma unroll
    for (int j = 0; j < 4; ++j) {
      int row = 16 * r + 4 * lg + j;
      f32x4 wr = *(const f32x4*)(exs + row * 16 + 4 * w);
      #pragma unroll
      for (int ci = 0; ci < 4; ++ci) {
        float v = racc[r][ci][j];
        v = v > 0.f ? v : 0.f;
        racc[r][ci][j] = v * wr[ci];
      }
    }

  // ---- Phase E: in-register segmented column sums; interior -> plain store, edge -> atomic
  unsigned long long m = bmask;
  while (m) {
    int a = __builtin_ctzll(m);
    m &= m - 1;
    int b = m ? __builtin_ctzll(m) : 64;
    int g = __shfl(gv, a, 64);
    f32x4 s = fzero4();
    #pragma unroll
    for (int r = 0; r < 4; ++r)
      #pragma unroll
      for (int j = 0; j < 4; ++j) {
        int row = 16 * r + 4 * lg + j;
        float msk = ((unsigned)(row - a) < (unsigned)(b - a)) ? 1.f : 0.f;
        #pragma unroll
        for (int ci = 0; ci < 4; ++ci) s[ci] = fmaf(msk, racc[r][ci][j], s[ci]);
      }
    #pragma unroll
    for (int ci = 0; ci < 4; ++ci) {
      s[ci] += __shfl_xor(s[ci], 16, 64);
      s[ci] += __shfl_xor(s[ci], 32, 64);
    }
    bool edge = (a == 0) || (b == 64);
    if (lane < 16) {
      float* dst = out + (size_t)g * GDIM + 64 * w + lane;
      if (edge) {
        atomicAdd(dst,      s[0]); atomicAdd(dst + 16, s[1]);
        atomicAdd(dst + 32, s[2]); atomicAdd(dst + 48, s[3]);
      } else {
        dst[0] = s[0]; dst[16] = s[1]; dst[32] = s[2]; dst[48] = s[3];
      }
    }
  }
}

// ---------------- epilogue: out[g][c] /= denom[g][c/16]; empty graphs -> 0 ----------------
__global__ void k_div(float* __restrict__ out, const float* __restrict__ denom) {
  int i = blockIdx.x * 256 + threadIdx.x;     // one float4 of out per thread
  if (i >= NG * GDIM / 4) return;
  float d = denom[(size_t)(i >> 6) * NH + ((i & 63) >> 2)];
  float r = d > 0.f ? 1.0f / d : 0.f;
  float4 v = ((float4*)out)[i];
  v.x *= r; v.y *= r; v.z *= r; v.w *= r;
  ((float4*)out)[i] = v;
}

extern "C" void kernel_launch(void* const* d_in, const int* in_sizes, int n_in,
                              void* d_out, int out_size, void* d_ws, size_t ws_size,
                              hipStream_t stream) {
  (void)in_sizes; (void)n_in; (void)out_size; (void)ws_size;
  const float* X  = (const float*)d_in[0];
  const int* seg  = (const int*)d_in[1];
  const float* s1 = (const float*)d_in[3];
  const float* s2 = (const float*)d_in[4];
  const float* t1 = (const float*)d_in[5];
  const float* t2 = (const float*)d_in[6];
  float* out = (float*)d_out;
  char* ws = (char*)d_ws;

  // ws layout: [0, 401408) weight frags bf16; [1<<19, +3.2MB) denom f32[NG][NH]
  unsigned short* WB = (unsigned short*)ws;
  float* denom = (float*)(ws + (1 << 19));

  k_prep<<<392, 256, 0, stream>>>(s1, s2, t1, t2, WB);
  k_zero<<<13282, 256, 0, stream>>>(out, denom);
  k_main<<<NTILES, 256, 0, stream>>>(X, WB, WB + 32768, WB + 98304, WB + 65536,
                                     seg, denom, out);
  k_div<<<12500, 256, 0, stream>>>(out, denom);
}